// Round 7
// baseline (215.545 us; speedup 1.0000x reference)
//
#include <hip/hip_runtime.h>
#include <hip/hip_bf16.h>

typedef __attribute__((ext_vector_type(4))) float f32x4;
typedef __attribute__((ext_vector_type(8))) short s16x8;

#define W2P_BYTES   8388608ull                 // 64*256*256 bf16
#define SLAB_FLOATS 1048576ull                 // 4096*256
#define WS_NEEDED   (W2P_BYTES + 7ull * SLAB_FLOATS * 4ull)

// ---------------------------------------------------------------------------
// k0: pack g_fc2_w (64,256,256) fp32 -> bf16 MFMA fragments, 1KB contiguous
// per fragment.  frag f = (n*8+ks)*16 + ct  (ct = col/16):
//   lane l, elem j = g2w[n][ks*32 + (l>>4)*8 + j][ct*16 + (l&15)]
// ---------------------------------------------------------------------------
__global__ __launch_bounds__(256) void k0_pack(const float* __restrict__ w2,
                                               ushort* __restrict__ out) {
  __shared__ float tile[32][257];
  const int n = blockIdx.x >> 3, ks = blockIdx.x & 7;
  const float* src = w2 + ((size_t)n * 256 + ks * 32) * 256;
  for (int i = threadIdx.x; i < 8192; i += 256)
    tile[i >> 8][i & 255] = src[i];
  __syncthreads();
#pragma unroll
  for (int q = 0; q < 4; ++q) {
    int chunk = q * 256 + threadIdx.x;
    int ct = chunk >> 6, l = chunk & 63;
    int g = l >> 4, cl = l & 15;
    s16x8 pk;
#pragma unroll
    for (int j = 0; j < 8; ++j) {
      __hip_bfloat16 h = __float2bfloat16(tile[g * 8 + j][ct * 16 + cl]);
      pk[j] = *reinterpret_cast<short*>(&h);
    }
    *reinterpret_cast<s16x8*>(out + ((size_t)(n * 8 + ks) * 1024 + chunk) * 8) = pk;
  }
}

// ---------------------------------------------------------------------------
// k1: f-path -> sparse_w (4096,64).  8 rows per block, 256 threads, grid 512.
// ---------------------------------------------------------------------------
__global__ __launch_bounds__(256) void k1_select(
    const float* __restrict__ x,
    const float* __restrict__ w1, const float* __restrict__ b1,
    const float* __restrict__ w2, const float* __restrict__ b2,
    const float* __restrict__ wsk, const float* __restrict__ bsk,
    const float* __restrict__ wg, const float* __restrict__ bg,
    const float* __restrict__ lng, const float* __restrict__ lnb,
    float* __restrict__ spw) {
  __shared__ float xs[8][64];
  __shared__ float t1[8][256];
  __shared__ float wvv[8][64];
  const int t = threadIdx.x;
  const int b0 = blockIdx.x * 8;
  if (t < 128) {
    const f32x4* xin = reinterpret_cast<const f32x4*>(x + (size_t)b0 * 64);
    reinterpret_cast<f32x4*>(&xs[0][0])[t] = xin[t];
  }
  __syncthreads();
  {  // t1[r][h] = elu(x @ f_fc1_w + b1), thread t = h
    float acc[8];
    float bias = b1[t];
#pragma unroll
    for (int r = 0; r < 8; ++r) acc[r] = bias;
    for (int n = 0; n < 64; ++n) {
      float w = w1[n * 256 + t];
#pragma unroll
      for (int r = 0; r < 8; ++r) acc[r] = fmaf(xs[r][n], w, acc[r]);
    }
#pragma unroll
    for (int r = 0; r < 8; ++r) {
      float z = acc[r];
      t1[r][t] = fmaxf(z, 0.f) + (__expf(fminf(z, 0.f)) - 1.f);
    }
  }
  __syncthreads();
  {  // h2 / skip / gate, thread = (nn = t&63, rg = t>>6), rows rg, rg+4
    const int nn = t & 63, rg = t >> 6;
    float a2[2], as_[2], ag[2];
    float bb2 = b2[nn], bbs = bsk[nn], bbg = bg[nn];
#pragma unroll
    for (int i = 0; i < 2; ++i) { a2[i] = bb2; as_[i] = bbs; ag[i] = bbg; }
    for (int h = 0; h < 256; ++h) {
      float w = w2[h * 64 + nn];
#pragma unroll
      for (int i = 0; i < 2; ++i) a2[i] = fmaf(t1[rg + 4 * i][h], w, a2[i]);
    }
    for (int m = 0; m < 64; ++m) {
      float ws_ = wsk[m * 64 + nn], wg_ = wg[m * 64 + nn];
#pragma unroll
      for (int i = 0; i < 2; ++i) {
        float xv = xs[rg + 4 * i][m];
        as_[i] = fmaf(xv, ws_, as_[i]);
        ag[i]  = fmaf(xv, wg_, ag[i]);
      }
    }
#pragma unroll
    for (int i = 0; i < 2; ++i) {
      float gt = __fdividef(1.f, 1.f + __expf(-ag[i]));
      wvv[rg + 4 * i][nn] = fmaf(gt, a2[i] - as_[i], as_[i]);
    }
  }
  __syncthreads();
  {  // LN over 64 + softmax over 64, wave handles 2 rows
    const int lane = t & 63, wid = t >> 6;
    float gl = lng[lane], bl = lnb[lane];
#pragma unroll
    for (int rr = 0; rr < 2; ++rr) {
      int r = wid * 2 + rr;
      float v = wvv[r][lane];
      float s = v;
      for (int m = 1; m < 64; m <<= 1) s += __shfl_xor(s, m);
      float mu = s * (1.f / 64.f);
      float d = v - mu;
      float q = d * d;
      for (int m = 1; m < 64; m <<= 1) q += __shfl_xor(q, m);
      float wn = d * rsqrtf(q * (1.f / 64.f) + 1e-5f) * gl + bl;
      float mx = wn;
      for (int m = 1; m < 64; m <<= 1) mx = fmaxf(mx, __shfl_xor(mx, m));
      float e = __expf(wn - mx);
      float se = e;
      for (int m = 1; m < 64; m <<= 1) se += __shfl_xor(se, m);
      spw[(size_t)(b0 + r) * 64 + lane] = __fdividef(e, se);
    }
  }
}

// ---------------------------------------------------------------------------
// k2: fused einsum + gate/skip + LN(H) + weighted accumulate.
// grid 1024: bid = btile*8 + nchunk (nchunk = bid&7 -> XCD-pinned weights).
// 256 threads / 4 waves, 32 rows x 8 n per block, 3 blocks/CU
// (__launch_bounds__(256,3) -> 168 unified regs: acc 32 + comb_acc 32 +
// W-dbuf 32 + temps fit WITHOUT spill).
// SWAPPED MFMA: acc[ct][rt] = mfma(Wfrag, actfrag) -> lane-local LN stats.
// comb_acc held in registers all 8 ni; ONE f32x4 store per tile at the end
// (nch 0 -> comb, nch 1..7 -> private ws slabs, k3 reduces; no atomics).
// ---------------------------------------------------------------------------
template <bool ATOMIC>
__global__ __launch_bounds__(256, 3) void k2_main(
    const float* __restrict__ x,
    const ushort* __restrict__ w2p,
    const float* __restrict__ fc1w, const float* __restrict__ fc1b,
    const float* __restrict__ fc2b,
    const float* __restrict__ skw, const float* __restrict__ skb,
    const float* __restrict__ gww, const float* __restrict__ gwb,
    const float* __restrict__ lng, const float* __restrict__ lnb,
    const float* __restrict__ spw,
    float* __restrict__ comb, float* __restrict__ slabs) {
  __shared__ __align__(16) char Ab[16384];   // act tile 32x256 bf16, swizzled
  __shared__ float xs[32][9];
  __shared__ float ss[32][9];
  __shared__ float sums[2][32][2];

  const int bid = blockIdx.x;
  const int nch = bid & 7;
  const int b0  = (bid >> 3) * 32;
  const int t = threadIdx.x;
  const int lane = t & 63;
  const int w = t >> 6;          // 0..3 (64-col band)
  const int g = lane >> 4;
  const int cl = lane & 15;
  const int n0 = nch * 8;

  { int r = t >> 3, j = t & 7;
    xs[r][j] = x[(size_t)(b0 + r) * 64 + nch * 8 + j];
    ss[r][j] = spw[(size_t)(b0 + r) * 64 + nch * 8 + j]; }
  if (t < 64) (&sums[0][0][0])[t] = 0.f;

  f32x4 comb_acc[4][2];
#pragma unroll
  for (int a = 0; a < 4; ++a)
#pragma unroll
    for (int b = 0; b < 2; ++b) comb_acc[a][b] = (f32x4){0.f, 0.f, 0.f, 0.f};

  const s16x8* wf = reinterpret_cast<const s16x8*>(w2p);
#define BFRAG(nn, kk, ct) \
  (wf + (((size_t)((nn) * 8 + (kk)) * 16 + w * 4 + (ct)) * 64 + lane))

  __syncthreads();

  for (int ni = 0; ni < 8; ++ni) {
    const int n = n0 + ni;
    // ---- issue W prefetch for ks=0,1 of THIS n (covered by A-gen) ----
    s16x8 bfa[4], bfb[4];
#pragma unroll
    for (int ct = 0; ct < 4; ++ct) {
      bfa[ct] = *BFRAG(n, 0, ct);
      bfb[ct] = *BFRAG(n, 1, ct);
    }

    // ---- A-gen: act[r][k] = elu(x[b0+r][n]*fc1w[n][k] + fc1b[n][k]) ----
    {
      const int kc = t & 31;
      const int rb = t >> 5;     // 0..7
      const float* w1p = fc1w + n * 256 + kc * 8;
      const float* b1p = fc1b + n * 256 + kc * 8;
      f32x4 wlo = *reinterpret_cast<const f32x4*>(w1p);
      f32x4 whi = *reinterpret_cast<const f32x4*>(w1p + 4);
      f32x4 blo = *reinterpret_cast<const f32x4*>(b1p);
      f32x4 bhi = *reinterpret_cast<const f32x4*>(b1p + 4);
#pragma unroll
      for (int i = 0; i < 4; ++i) {
        int r = rb + 8 * i;
        float xv = xs[r][ni];
        s16x8 pk;
#pragma unroll
        for (int j = 0; j < 4; ++j) {
          float z0 = fmaf(xv, wlo[j], blo[j]);
          float z1 = fmaf(xv, whi[j], bhi[j]);
          float e0 = fmaxf(z0, 0.f) + (__expf(fminf(z0, 0.f)) - 1.f);
          float e1 = fmaxf(z1, 0.f) + (__expf(fminf(z1, 0.f)) - 1.f);
          __hip_bfloat16 h0 = __float2bfloat16(e0);
          __hip_bfloat16 h1 = __float2bfloat16(e1);
          pk[j]     = *reinterpret_cast<short*>(&h0);
          pk[j + 4] = *reinterpret_cast<short*>(&h1);
        }
        *reinterpret_cast<s16x8*>(Ab + r * 512 + ((kc << 4) ^ ((r & 7) << 4))) = pk;
      }
    }
    __syncthreads();   // Ab ready; all waves past previous pass-2

    f32x4 acc[4][2];   // [ct][rt]
#pragma unroll
    for (int a = 0; a < 4; ++a)
#pragma unroll
      for (int b = 0; b < 2; ++b) acc[a][b] = (f32x4){0.f, 0.f, 0.f, 0.f};

#pragma unroll
    for (int ks = 0; ks < 8; ++ks) {
      s16x8* cur = (ks & 1) ? bfb : bfa;
      s16x8 af[2];
#pragma unroll
      for (int rt = 0; rt < 2; ++rt) {
        int row = rt * 16 + cl;
        af[rt] = *reinterpret_cast<const s16x8*>(
            Ab + row * 512 + (((ks * 4 + g) << 4) ^ ((row & 7) << 4)));
      }
#pragma unroll
      for (int ct = 0; ct < 4; ++ct)
#pragma unroll
        for (int rt = 0; rt < 2; ++rt)
          acc[ct][rt] = __builtin_amdgcn_mfma_f32_16x16x32_bf16(
              cur[ct], af[rt], acc[ct][rt], 0, 0, 0);
      if (ks < 6) {
#pragma unroll
        for (int ct = 0; ct < 4; ++ct) cur[ct] = *BFRAG(n, ks + 2, ct);
      }
    }

    // ---- epilogue pass 1: gate mix + lane-local row stats ----
    const int par = ni & 1;
    {
      float xr[2], rsum[2], rsq[2];
#pragma unroll
      for (int rt = 0; rt < 2; ++rt) {
        xr[rt] = xs[rt * 16 + cl][ni];
        rsum[rt] = 0.f;
        rsq[rt] = 0.f;
      }
#pragma unroll
      for (int ct = 0; ct < 4; ++ct) {
        const int c4 = n * 256 + w * 64 + ct * 16 + g * 4;
        f32x4 f2b4 = *reinterpret_cast<const f32x4*>(fc2b + c4);
        f32x4 sw4  = *reinterpret_cast<const f32x4*>(skw + c4);
        f32x4 sb4  = *reinterpret_cast<const f32x4*>(skb + c4);
        f32x4 gw4  = *reinterpret_cast<const f32x4*>(gww + c4);
        f32x4 gb4  = *reinterpret_cast<const f32x4*>(gwb + c4);
#pragma unroll
        for (int rt = 0; rt < 2; ++rt) {
#pragma unroll
          for (int j = 0; j < 4; ++j) {
            float hv = acc[ct][rt][j] + f2b4[j];
            float sk = fmaf(xr[rt], sw4[j], sb4[j]);
            float gv = __fdividef(1.f, 1.f + __expf(-fmaf(xr[rt], gw4[j], gb4[j])));
            float p = fmaf(gv, hv - sk, sk);
            acc[ct][rt][j] = p;
            rsum[rt] += p;
            rsq[rt] = fmaf(p, p, rsq[rt]);
          }
        }
      }
#pragma unroll
      for (int rt = 0; rt < 2; ++rt) {
        rsum[rt] += __shfl_xor(rsum[rt], 16);
        rsum[rt] += __shfl_xor(rsum[rt], 32);
        rsq[rt]  += __shfl_xor(rsq[rt], 16);
        rsq[rt]  += __shfl_xor(rsq[rt], 32);
      }
      if (g == 0) {
#pragma unroll
        for (int rt = 0; rt < 2; ++rt) {
          atomicAdd(&sums[par][rt * 16 + cl][0], rsum[rt]);
          atomicAdd(&sums[par][rt * 16 + cl][1], rsq[rt]);
        }
      }
    }
    if (t < 64) (&sums[par ^ 1][0][0])[t] = 0.f;  // zero parity for ni+1
    __syncthreads();   // sums ready

    // ---- pass 2: normalize + softmax-weighted accumulate (registers) ----
    {
      float rsv[2], mrs[2], svv[2];
#pragma unroll
      for (int rt = 0; rt < 2; ++rt) {
        int row = rt * 16 + cl;
        float s0 = sums[par][row][0], s1 = sums[par][row][1];
        float mu = s0 * (1.f / 256.f);
        float rs = rsqrtf(fmaxf(s1 * (1.f / 256.f) - mu * mu, 0.f) + 1e-5f);
        rsv[rt] = rs;
        mrs[rt] = -mu * rs;
        svv[rt] = ss[row][ni];
      }
#pragma unroll
      for (int ct = 0; ct < 4; ++ct) {
        const int c4 = n * 256 + w * 64 + ct * 16 + g * 4;
        f32x4 lg4 = *reinterpret_cast<const f32x4*>(lng + c4);
        f32x4 lb4 = *reinterpret_cast<const f32x4*>(lnb + c4);
#pragma unroll
        for (int rt = 0; rt < 2; ++rt) {
#pragma unroll
          for (int j = 0; j < 4; ++j) {
            float tnorm = fmaf(acc[ct][rt][j], rsv[rt], mrs[rt]);
            float emb = fmaf(tnorm, lg4[j], lb4[j]);
            comb_acc[ct][rt][j] = fmaf(svv[rt], emb, comb_acc[ct][rt][j]);
          }
        }
      }
    }
  }
#undef BFRAG

  float* outp;
  if (ATOMIC) outp = comb;
  else outp = (nch == 0) ? comb : slabs + (size_t)(nch - 1) * SLAB_FLOATS;
#pragma unroll
  for (int ct = 0; ct < 4; ++ct)
#pragma unroll
    for (int rt = 0; rt < 2; ++rt) {
      size_t idx = (size_t)(b0 + rt * 16 + cl) * 256 + w * 64 + ct * 16 + g * 4;
      if (ATOMIC) {
#pragma unroll
        for (int j = 0; j < 4; ++j)
          atomicAdd(&outp[idx + j], comb_acc[ct][rt][j]);
      } else {
        *reinterpret_cast<f32x4*>(outp + idx) = comb_acc[ct][rt];
      }
    }
}

// ---------------------------------------------------------------------------
// k3: comb += sum of the 7 partial slabs.  grid 1024 x 256, f32x4 per thread.
// ---------------------------------------------------------------------------
__global__ __launch_bounds__(256) void k3_reduce(float* __restrict__ comb,
                                                 const float* __restrict__ slabs) {
  size_t i = (size_t)blockIdx.x * 256 + threadIdx.x;   // f32x4 index
  f32x4 v = reinterpret_cast<const f32x4*>(comb)[i];
#pragma unroll
  for (int s = 0; s < 7; ++s)
    v += reinterpret_cast<const f32x4*>(slabs)[s * (SLAB_FLOATS / 4) + i];
  reinterpret_cast<f32x4*>(comb)[i] = v;
}

// ---------------------------------------------------------------------------
extern "C" void kernel_launch(void* const* d_in, const int* in_sizes, int n_in,
                              void* d_out, int out_size, void* d_ws, size_t ws_size,
                              hipStream_t stream) {
  const float* x   = (const float*)d_in[0];
  const float* f1w = (const float*)d_in[1];
  const float* f1b = (const float*)d_in[2];
  const float* f2w = (const float*)d_in[3];
  const float* f2b = (const float*)d_in[4];
  const float* fsw = (const float*)d_in[5];
  const float* fsb = (const float*)d_in[6];
  const float* fgw = (const float*)d_in[7];
  const float* fgb = (const float*)d_in[8];
  const float* flg = (const float*)d_in[9];
  const float* flb = (const float*)d_in[10];
  const float* g1w = (const float*)d_in[11];
  const float* g1b = (const float*)d_in[12];
  const float* g2w = (const float*)d_in[13];
  const float* g2b = (const float*)d_in[14];
  const float* gsw = (const float*)d_in[15];
  const float* gsb = (const float*)d_in[16];
  const float* ggw = (const float*)d_in[17];
  const float* ggb = (const float*)d_in[18];
  const float* glg = (const float*)d_in[19];
  const float* glb = (const float*)d_in[20];

  float* out  = (float*)d_out;
  float* comb = out;                          // (4096,256)
  float* spw  = out + (size_t)4096 * 256;     // (4096,64)
  ushort* w2p = (ushort*)d_ws;                // 8.4 MB packed bf16 W-frags
  float* slabs = (float*)((char*)d_ws + W2P_BYTES);  // 7 x 4 MB partials

  k0_pack<<<512, 256, 0, stream>>>(g2w, w2p);
  k1_select<<<512, 256, 0, stream>>>(x, f1w, f1b, f2w, f2b, fsw, fsb,
                                     fgw, fgb, flg, flb, spw);
  if (ws_size >= WS_NEEDED) {
    k2_main<false><<<1024, 256, 0, stream>>>(x, w2p, g1w, g1b, g2b, gsw, gsb,
                                             ggw, ggb, glg, glb, spw, comb, slabs);
    k3_reduce<<<1024, 256, 0, stream>>>(comb, slabs);
  } else {
    hipMemsetAsync(comb, 0, (size_t)4096 * 256 * sizeof(float), stream);
    k2_main<true><<<1024, 256, 0, stream>>>(x, w2p, g1w, g1b, g2b, gsw, gsb,
                                            ggw, ggb, glg, glb, spw, comb, slabs);
  }
}

// Round 8
// 151.634 us; speedup vs baseline: 1.4215x; 1.4215x over previous
//
#include <hip/hip_runtime.h>
#include <hip/hip_bf16.h>

typedef __attribute__((ext_vector_type(4))) float f32x4;
typedef __attribute__((ext_vector_type(8))) short s16x8;

#define W2P_BYTES   8388608ull                 // 64*256*256 bf16
#define SLAB_FLOATS 1048576ull                 // 4096*256
#define WS_NEEDED   (W2P_BYTES + 7ull * SLAB_FLOATS * 4ull)

// ---------------------------------------------------------------------------
// k0: pack g_fc2_w (64,256,256) fp32 -> bf16 MFMA fragments, 1KB contiguous
// per fragment.  frag f = (n*8+ks)*16 + ct  (ct = col/16):
//   lane l, elem j = g2w[n][ks*32 + (l>>4)*8 + j][ct*16 + (l&15)]
// ---------------------------------------------------------------------------
__global__ __launch_bounds__(256) void k0_pack(const float* __restrict__ w2,
                                               ushort* __restrict__ out) {
  __shared__ float tile[32][257];
  const int n = blockIdx.x >> 3, ks = blockIdx.x & 7;
  const float* src = w2 + ((size_t)n * 256 + ks * 32) * 256;
  for (int i = threadIdx.x; i < 8192; i += 256)
    tile[i >> 8][i & 255] = src[i];
  __syncthreads();
#pragma unroll
  for (int q = 0; q < 4; ++q) {
    int chunk = q * 256 + threadIdx.x;
    int ct = chunk >> 6, l = chunk & 63;
    int g = l >> 4, cl = l & 15;
    s16x8 pk;
#pragma unroll
    for (int j = 0; j < 8; ++j) {
      __hip_bfloat16 h = __float2bfloat16(tile[g * 8 + j][ct * 16 + cl]);
      pk[j] = *reinterpret_cast<short*>(&h);
    }
    *reinterpret_cast<s16x8*>(out + ((size_t)(n * 8 + ks) * 1024 + chunk) * 8) = pk;
  }
}

// ---------------------------------------------------------------------------
// k1: f-path -> sparse_w (4096,64).  8 rows per block, 256 threads, grid 512.
// ---------------------------------------------------------------------------
__global__ __launch_bounds__(256) void k1_select(
    const float* __restrict__ x,
    const float* __restrict__ w1, const float* __restrict__ b1,
    const float* __restrict__ w2, const float* __restrict__ b2,
    const float* __restrict__ wsk, const float* __restrict__ bsk,
    const float* __restrict__ wg, const float* __restrict__ bg,
    const float* __restrict__ lng, const float* __restrict__ lnb,
    float* __restrict__ spw) {
  __shared__ float xs[8][64];
  __shared__ float t1[8][256];
  __shared__ float wvv[8][64];
  const int t = threadIdx.x;
  const int b0 = blockIdx.x * 8;
  if (t < 128) {
    const f32x4* xin = reinterpret_cast<const f32x4*>(x + (size_t)b0 * 64);
    reinterpret_cast<f32x4*>(&xs[0][0])[t] = xin[t];
  }
  __syncthreads();
  {  // t1[r][h] = elu(x @ f_fc1_w + b1), thread t = h
    float acc[8];
    float bias = b1[t];
#pragma unroll
    for (int r = 0; r < 8; ++r) acc[r] = bias;
    for (int n = 0; n < 64; ++n) {
      float w = w1[n * 256 + t];
#pragma unroll
      for (int r = 0; r < 8; ++r) acc[r] = fmaf(xs[r][n], w, acc[r]);
    }
#pragma unroll
    for (int r = 0; r < 8; ++r) {
      float z = acc[r];
      t1[r][t] = fmaxf(z, 0.f) + (__expf(fminf(z, 0.f)) - 1.f);
    }
  }
  __syncthreads();
  {  // h2 / skip / gate, thread = (nn = t&63, rg = t>>6), rows rg, rg+4
    const int nn = t & 63, rg = t >> 6;
    float a2[2], as_[2], ag[2];
    float bb2 = b2[nn], bbs = bsk[nn], bbg = bg[nn];
#pragma unroll
    for (int i = 0; i < 2; ++i) { a2[i] = bb2; as_[i] = bbs; ag[i] = bbg; }
    for (int h = 0; h < 256; ++h) {
      float w = w2[h * 64 + nn];
#pragma unroll
      for (int i = 0; i < 2; ++i) a2[i] = fmaf(t1[rg + 4 * i][h], w, a2[i]);
    }
    for (int m = 0; m < 64; ++m) {
      float ws_ = wsk[m * 64 + nn], wg_ = wg[m * 64 + nn];
#pragma unroll
      for (int i = 0; i < 2; ++i) {
        float xv = xs[rg + 4 * i][m];
        as_[i] = fmaf(xv, ws_, as_[i]);
        ag[i]  = fmaf(xv, wg_, ag[i]);
      }
    }
#pragma unroll
    for (int i = 0; i < 2; ++i) {
      float gt = __fdividef(1.f, 1.f + __expf(-ag[i]));
      wvv[rg + 4 * i][nn] = fmaf(gt, a2[i] - as_[i], as_[i]);
    }
  }
  __syncthreads();
  {  // LN over 64 + softmax over 64, wave handles 2 rows
    const int lane = t & 63, wid = t >> 6;
    float gl = lng[lane], bl = lnb[lane];
#pragma unroll
    for (int rr = 0; rr < 2; ++rr) {
      int r = wid * 2 + rr;
      float v = wvv[r][lane];
      float s = v;
      for (int m = 1; m < 64; m <<= 1) s += __shfl_xor(s, m);
      float mu = s * (1.f / 64.f);
      float d = v - mu;
      float q = d * d;
      for (int m = 1; m < 64; m <<= 1) q += __shfl_xor(q, m);
      float wn = d * rsqrtf(q * (1.f / 64.f) + 1e-5f) * gl + bl;
      float mx = wn;
      for (int m = 1; m < 64; m <<= 1) mx = fmaxf(mx, __shfl_xor(mx, m));
      float e = __expf(wn - mx);
      float se = e;
      for (int m = 1; m < 64; m <<= 1) se += __shfl_xor(se, m);
      spw[(size_t)(b0 + r) * 64 + lane] = __fdividef(e, se);
    }
  }
}

// ---------------------------------------------------------------------------
// k2: fused einsum + gate/skip + LN(H) + weighted accumulate.
// grid 1024: bid = btile*8 + nchunk (nchunk = bid&7 -> XCD-pinned weights).
// 512 threads / 8 waves, 32 rows x 8 n per block.  Wave w owns cols
// [w*32, w*32+32) x 32 rows -> acc[2][2] + comb_acc[2][2] = 32 acc-class regs,
// W-dbuf 32, af 16, temps: ~115 regs -> __launch_bounds__(512,4) = 128-reg cap,
// 2 blocks/CU = 16 waves/CU, grid 1024 = exactly 2 full rounds (no tail).
// SWAPPED MFMA: acc[ct][rt] = mfma(Wfrag, actfrag) -> lane-local LN stats.
// Output: one f32x4 store per tile (nch 0 -> comb, nch 1..7 -> ws slabs).
// ---------------------------------------------------------------------------
template <bool ATOMIC>
__global__ __launch_bounds__(512, 4) void k2_main(
    const float* __restrict__ x,
    const ushort* __restrict__ w2p,
    const float* __restrict__ fc1w, const float* __restrict__ fc1b,
    const float* __restrict__ fc2b,
    const float* __restrict__ skw, const float* __restrict__ skb,
    const float* __restrict__ gww, const float* __restrict__ gwb,
    const float* __restrict__ lng, const float* __restrict__ lnb,
    const float* __restrict__ spw,
    float* __restrict__ comb, float* __restrict__ slabs) {
  __shared__ __align__(16) char Ab[16384];   // act tile 32x256 bf16, swizzled
  __shared__ float xs[32][9];
  __shared__ float ss[32][9];
  __shared__ float sums[2][32][2];

  const int bid = blockIdx.x;
  const int nch = bid & 7;
  const int b0  = (bid >> 3) * 32;
  const int t = threadIdx.x;
  const int lane = t & 63;
  const int w = t >> 6;          // 0..7 (32-col band)
  const int g = lane >> 4;
  const int cl = lane & 15;
  const int n0 = nch * 8;

  if (t < 256) {
    int r = t >> 3, j = t & 7;
    xs[r][j] = x[(size_t)(b0 + r) * 64 + nch * 8 + j];
    ss[r][j] = spw[(size_t)(b0 + r) * 64 + nch * 8 + j];
  }
  if (t < 64) (&sums[0][0][0])[t] = 0.f;

  f32x4 comb_acc[2][2];
#pragma unroll
  for (int a = 0; a < 2; ++a)
#pragma unroll
    for (int b = 0; b < 2; ++b) comb_acc[a][b] = (f32x4){0.f, 0.f, 0.f, 0.f};

  const s16x8* wf = reinterpret_cast<const s16x8*>(w2p);
#define BFRAG(nn, kk, ct) \
  (wf + (((size_t)((nn) * 8 + (kk)) * 16 + w * 2 + (ct)) * 64 + lane))

  __syncthreads();

  for (int ni = 0; ni < 8; ++ni) {
    const int n = n0 + ni;
    // ---- issue W prefetch for ks=0,1 of THIS n (covered by A-gen) ----
    s16x8 bfa[2], bfb[2];
#pragma unroll
    for (int ct = 0; ct < 2; ++ct) {
      bfa[ct] = *BFRAG(n, 0, ct);
      bfb[ct] = *BFRAG(n, 1, ct);
    }

    // ---- A-gen: act[r][k] = elu(x[b0+r][n]*fc1w[n][k] + fc1b[n][k]) ----
    {
      const int kc = t & 31;
      const int rb = t >> 5;     // 0..15
      const float* w1p = fc1w + n * 256 + kc * 8;
      const float* b1p = fc1b + n * 256 + kc * 8;
      f32x4 wlo = *reinterpret_cast<const f32x4*>(w1p);
      f32x4 whi = *reinterpret_cast<const f32x4*>(w1p + 4);
      f32x4 blo = *reinterpret_cast<const f32x4*>(b1p);
      f32x4 bhi = *reinterpret_cast<const f32x4*>(b1p + 4);
#pragma unroll
      for (int i = 0; i < 2; ++i) {
        int r = rb + 16 * i;
        float xv = xs[r][ni];
        s16x8 pk;
#pragma unroll
        for (int j = 0; j < 4; ++j) {
          float z0 = fmaf(xv, wlo[j], blo[j]);
          float z1 = fmaf(xv, whi[j], bhi[j]);
          float e0 = fmaxf(z0, 0.f) + (__expf(fminf(z0, 0.f)) - 1.f);
          float e1 = fmaxf(z1, 0.f) + (__expf(fminf(z1, 0.f)) - 1.f);
          __hip_bfloat16 h0 = __float2bfloat16(e0);
          __hip_bfloat16 h1 = __float2bfloat16(e1);
          pk[j]     = *reinterpret_cast<short*>(&h0);
          pk[j + 4] = *reinterpret_cast<short*>(&h1);
        }
        *reinterpret_cast<s16x8*>(Ab + r * 512 + ((kc << 4) ^ ((r & 7) << 4))) = pk;
      }
    }
    __syncthreads();   // Ab ready; all waves past previous pass-2

    f32x4 acc[2][2];   // [ct][rt]
#pragma unroll
    for (int a = 0; a < 2; ++a)
#pragma unroll
      for (int b = 0; b < 2; ++b) acc[a][b] = (f32x4){0.f, 0.f, 0.f, 0.f};

#pragma unroll
    for (int ks = 0; ks < 8; ++ks) {
      s16x8* cur = (ks & 1) ? bfb : bfa;
      s16x8 af[2];
#pragma unroll
      for (int rt = 0; rt < 2; ++rt) {
        int row = rt * 16 + cl;
        af[rt] = *reinterpret_cast<const s16x8*>(
            Ab + row * 512 + (((ks * 4 + g) << 4) ^ ((row & 7) << 4)));
      }
#pragma unroll
      for (int ct = 0; ct < 2; ++ct)
#pragma unroll
        for (int rt = 0; rt < 2; ++rt)
          acc[ct][rt] = __builtin_amdgcn_mfma_f32_16x16x32_bf16(
              cur[ct], af[rt], acc[ct][rt], 0, 0, 0);
      if (ks < 6) {
#pragma unroll
        for (int ct = 0; ct < 2; ++ct) cur[ct] = *BFRAG(n, ks + 2, ct);
      }
    }

    // ---- epilogue pass 1: gate mix + lane-local row stats ----
    const int par = ni & 1;
    {
      float xr[2], rsum[2], rsq[2];
#pragma unroll
      for (int rt = 0; rt < 2; ++rt) {
        xr[rt] = xs[rt * 16 + cl][ni];
        rsum[rt] = 0.f;
        rsq[rt] = 0.f;
      }
#pragma unroll
      for (int ct = 0; ct < 2; ++ct) {
        const int c4 = n * 256 + (w * 2 + ct) * 16 + g * 4;
        f32x4 f2b4 = *reinterpret_cast<const f32x4*>(fc2b + c4);
        f32x4 sw4  = *reinterpret_cast<const f32x4*>(skw + c4);
        f32x4 sb4  = *reinterpret_cast<const f32x4*>(skb + c4);
        f32x4 gw4  = *reinterpret_cast<const f32x4*>(gww + c4);
        f32x4 gb4  = *reinterpret_cast<const f32x4*>(gwb + c4);
#pragma unroll
        for (int rt = 0; rt < 2; ++rt) {
#pragma unroll
          for (int j = 0; j < 4; ++j) {
            float hv = acc[ct][rt][j] + f2b4[j];
            float sk = fmaf(xr[rt], sw4[j], sb4[j]);
            float gv = __fdividef(1.f, 1.f + __expf(-fmaf(xr[rt], gw4[j], gb4[j])));
            float p = fmaf(gv, hv - sk, sk);
            acc[ct][rt][j] = p;
            rsum[rt] += p;
            rsq[rt] = fmaf(p, p, rsq[rt]);
          }
        }
      }
#pragma unroll
      for (int rt = 0; rt < 2; ++rt) {
        rsum[rt] += __shfl_xor(rsum[rt], 16);
        rsum[rt] += __shfl_xor(rsum[rt], 32);
        rsq[rt]  += __shfl_xor(rsq[rt], 16);
        rsq[rt]  += __shfl_xor(rsq[rt], 32);
      }
      if (g == 0) {
#pragma unroll
        for (int rt = 0; rt < 2; ++rt) {
          atomicAdd(&sums[par][rt * 16 + cl][0], rsum[rt]);
          atomicAdd(&sums[par][rt * 16 + cl][1], rsq[rt]);
        }
      }
    }
    if (t < 64) (&sums[par ^ 1][0][0])[t] = 0.f;  // zero parity for ni+1
    __syncthreads();   // sums ready

    // ---- pass 2: normalize + softmax-weighted accumulate (registers) ----
    {
      float rsv[2], mrs[2], svv[2];
#pragma unroll
      for (int rt = 0; rt < 2; ++rt) {
        int row = rt * 16 + cl;
        float s0 = sums[par][row][0], s1 = sums[par][row][1];
        float mu = s0 * (1.f / 256.f);
        float rs = rsqrtf(fmaxf(s1 * (1.f / 256.f) - mu * mu, 0.f) + 1e-5f);
        rsv[rt] = rs;
        mrs[rt] = -mu * rs;
        svv[rt] = ss[row][ni];
      }
#pragma unroll
      for (int ct = 0; ct < 2; ++ct) {
        const int c4 = n * 256 + (w * 2 + ct) * 16 + g * 4;
        f32x4 lg4 = *reinterpret_cast<const f32x4*>(lng + c4);
        f32x4 lb4 = *reinterpret_cast<const f32x4*>(lnb + c4);
#pragma unroll
        for (int rt = 0; rt < 2; ++rt) {
#pragma unroll
          for (int j = 0; j < 4; ++j) {
            float tnorm = fmaf(acc[ct][rt][j], rsv[rt], mrs[rt]);
            float emb = fmaf(tnorm, lg4[j], lb4[j]);
            comb_acc[ct][rt][j] = fmaf(svv[rt], emb, comb_acc[ct][rt][j]);
          }
        }
      }
    }
  }
#undef BFRAG

  float* outp;
  if (ATOMIC) outp = comb;
  else outp = (nch == 0) ? comb : slabs + (size_t)(nch - 1) * SLAB_FLOATS;
#pragma unroll
  for (int ct = 0; ct < 2; ++ct)
#pragma unroll
    for (int rt = 0; rt < 2; ++rt) {
      size_t idx = (size_t)(b0 + rt * 16 + cl) * 256 + (w * 2 + ct) * 16 + g * 4;
      if (ATOMIC) {
#pragma unroll
        for (int j = 0; j < 4; ++j)
          atomicAdd(&outp[idx + j], comb_acc[ct][rt][j]);
      } else {
        *reinterpret_cast<f32x4*>(outp + idx) = comb_acc[ct][rt];
      }
    }
}

// ---------------------------------------------------------------------------
// k3: comb += sum of the 7 partial slabs.  grid 1024 x 256, f32x4 per thread.
// ---------------------------------------------------------------------------
__global__ __launch_bounds__(256) void k3_reduce(float* __restrict__ comb,
                                                 const float* __restrict__ slabs) {
  size_t i = (size_t)blockIdx.x * 256 + threadIdx.x;   // f32x4 index
  f32x4 v = reinterpret_cast<const f32x4*>(comb)[i];
#pragma unroll
  for (int s = 0; s < 7; ++s)
    v += reinterpret_cast<const f32x4*>(slabs)[s * (SLAB_FLOATS / 4) + i];
  reinterpret_cast<f32x4*>(comb)[i] = v;
}

// ---------------------------------------------------------------------------
extern "C" void kernel_launch(void* const* d_in, const int* in_sizes, int n_in,
                              void* d_out, int out_size, void* d_ws, size_t ws_size,
                              hipStream_t stream) {
  const float* x   = (const float*)d_in[0];
  const float* f1w = (const float*)d_in[1];
  const float* f1b = (const float*)d_in[2];
  const float* f2w = (const float*)d_in[3];
  const float* f2b = (const float*)d_in[4];
  const float* fsw = (const float*)d_in[5];
  const float* fsb = (const float*)d_in[6];
  const float* fgw = (const float*)d_in[7];
  const float* fgb = (const float*)d_in[8];
  const float* flg = (const float*)d_in[9];
  const float* flb = (const float*)d_in[10];
  const float* g1w = (const float*)d_in[11];
  const float* g1b = (const float*)d_in[12];
  const float* g2w = (const float*)d_in[13];
  const float* g2b = (const float*)d_in[14];
  const float* gsw = (const float*)d_in[15];
  const float* gsb = (const float*)d_in[16];
  const float* ggw = (const float*)d_in[17];
  const float* ggb = (const float*)d_in[18];
  const float* glg = (const float*)d_in[19];
  const float* glb = (const float*)d_in[20];

  float* out  = (float*)d_out;
  float* comb = out;                          // (4096,256)
  float* spw  = out + (size_t)4096 * 256;     // (4096,64)
  ushort* w2p = (ushort*)d_ws;                // 8.4 MB packed bf16 W-frags
  float* slabs = (float*)((char*)d_ws + W2P_BYTES);  // 7 x 4 MB partials

  k0_pack<<<512, 256, 0, stream>>>(g2w, w2p);
  k1_select<<<512, 256, 0, stream>>>(x, f1w, f1b, f2w, f2b, fsw, fsb,
                                     fgw, fgb, flg, flb, spw);
  if (ws_size >= WS_NEEDED) {
    k2_main<false><<<1024, 512, 0, stream>>>(x, w2p, g1w, g1b, g2b, gsw, gsb,
                                             ggw, ggb, glg, glb, spw, comb, slabs);
    k3_reduce<<<1024, 256, 0, stream>>>(comb, slabs);
  } else {
    hipMemsetAsync(comb, 0, (size_t)4096 * 256 * sizeof(float), stream);
    k2_main<true><<<1024, 512, 0, stream>>>(x, w2p, g1w, g1b, g2b, gsw, gsb,
                                            ggw, ggb, glg, glb, spw, comb, slabs);
  }
}